// Round 10
// baseline (1387.233 us; speedup 1.0000x reference)
//
#include <hip/hip_runtime.h>
#include <math.h>

// Problem constants (fixed by setup_inputs)
constexpr int Bb = 128;   // batch
constexpr int Nn = 2048;  // input capsules
constexpr int Dd = 8;     // input capsule dim
constexpr int Jj = 32;    // output capsules
constexpr int Pp = 16;    // output capsule dim

// Tiling: R4/R7-proven. 512-thread blocks, 8 waves, BT=2 batches/wave.
// GRID=512 = exactly 2 blocks/CU (co-resident by capacity: LDS 24.6K->6/CU,
// waves 8->4/CU, VGPR<=64->4/CU; guide rule k=w*4/(B/64)=2 -> grid<=512 OK).
constexpr int BT = 2;
constexpr int WV = 8;
constexpr int BB = BT * WV;      // 16 batches per block
constexpr int BN = 32;           // n per block
constexpr int NBC = Bb / BB;     // 8
constexpr int NNC = Nn / BN;     // 64
constexpr int GRID = NBC * NNC;  // 512
constexpr int SZ = Bb * Jj * Pp; // 65536 floats

typedef _Float16 half2v __attribute__((ext_vector_type(2)));

#if __has_builtin(__builtin_amdgcn_fdot2)
__device__ inline float fdot2(half2v a, half2v b, float c) {
    return __builtin_amdgcn_fdot2(a, b, c, false);
}
#else
__device__ inline float fdot2(half2v a, half2v b, float c) {
    return (float)a.x * (float)b.x + (float)a.y * (float)b.y + c;
}
#endif

__device__ inline half2v bch2(unsigned u) { return __builtin_bit_cast(half2v, u); }
__device__ inline unsigned pkh2(float lo, float hi) {
    half2v h; h.x = (_Float16)lo; h.y = (_Float16)hi;   // v_cvt_f16_f32 (RTN)
    return __builtin_bit_cast(unsigned, h);
}

// Manual grid barrier. Safe because all GRID blocks are co-resident (capacity
// arithmetic above). Counters zeroed by hipMemsetAsync before each launch.
// Release: threadfence + agent-scope fetch_add. Acquire: agent-scope load
// spin on tid 0, then syncthreads + threadfence (invalidates stale L1/L2-XCD
// lines so post-barrier reads see other XCDs' plain stores).
__device__ inline void gbar(unsigned* ctr, int tid) {
    __threadfence();
    __syncthreads();
    if (tid == 0) {
        __hip_atomic_fetch_add(ctr, 1u, __ATOMIC_ACQ_REL,
                               __HIP_MEMORY_SCOPE_AGENT);
        while (__hip_atomic_load(ctr, __ATOMIC_ACQUIRE,
                                 __HIP_MEMORY_SCOPE_AGENT) < (unsigned)GRID) {
            __builtin_amdgcn_s_sleep(8);
        }
    }
    __syncthreads();
    __threadfence();
}

// Fused 3-pass routing. Route body is R7-VERBATIM (proven 55.3 us/pass,
// 52 VGPR, 0 bank conflicts); between passes: gbar + distributed
// reduce+squash (each block owns 32 float4 of S; scratch reuses wbuf).
__global__ __launch_bounds__(512, 4)
void fused_k(const float* __restrict__ x, const float* __restrict__ W,
             float* __restrict__ Sp, float* __restrict__ OS,
             float* __restrict__ out, unsigned* __restrict__ bar)
{
    __shared__ uint4 wbuf[2][512];   // 2 x 8 KB fp16 W double buffer
    __shared__ uint4 xs[BB * BN];    // 8 KB fp16 x tile: [b][n] -> 8 halves

    const int tid  = threadIdx.x;
    const int wave = tid >> 6;
    const int lane = tid & 63;

    const int id  = blockIdx.x;
    const int xcd = id & 7;
    const int bc  = (id >> 3) & 7;
    const int nch = id >> 6;               // 0..7
    const int nc  = xcd + 8 * nch;         // 0..63
    const int b0  = bc * BB;
    const int n0  = nc * BN;
    const int j   = lane >> 1;
    const int hp  = lane & 1;              // p-half

    // ---- stage x tile as fp16 ONCE (persists across passes) ----
    {
        const int b = tid >> 5, n = tid & 31;
        const float4* src = reinterpret_cast<const float4*>(
            x + ((size_t)(b0 + b) * Nn + n0 + n) * Dd);
        float4 a = src[0], c4 = src[1];
        uint4 o;
        o.x = pkh2(a.x, a.y);  o.y = pkh2(a.z, a.w);
        o.z = pkh2(c4.x, c4.y); o.w = pkh2(c4.z, c4.w);
        xs[b * BN + n] = o;
    }

    // ---- W staging: thread t -> (j = t>>4, p = t&15); 2 float4 -> 1 uint4 ----
    const float4* Wg = reinterpret_cast<const float4*>(W);
    const int sj = tid >> 4;                    // j
    const int sp = tid & 15;                    // p
    const int sl = sj * 2 + (sp >> 3);          // l for this chunk
    const int spp = sp & 7;                     // pp
    const int wslot = spp * 64 + ((sl + spp) & 63);

    float4 sta, stb;
    auto load_slice = [&](int n) {
        const size_t base = (size_t)n * 32 + sp * 2 + (size_t)sj * ((size_t)Nn * 32);
        sta = Wg[base];
        stb = Wg[base + 1];
    };
    auto store_slice = [&](int buf) {
        uint4 o;
        o.x = pkh2(sta.x, sta.y);  o.y = pkh2(sta.z, sta.w);
        o.z = pkh2(stb.x, stb.y);  o.w = pkh2(stb.z, stb.w);
        wbuf[buf][wslot] = o;
    };

    const uint4* xw = xs + (size_t)(wave * BT) * BN;   // this wave's x rows

    for (int pass = 0; pass < 3; ++pass) {
        // Output-sum fragment for logits (passes 1,2); OS valid after gbar.
        float osum[BT][8];
        if (pass > 0) {
            #pragma unroll
            for (int bb = 0; bb < BT; ++bb) {
                const float4* op = reinterpret_cast<const float4*>(
                    OS + ((size_t)(b0 + wave * BT + bb) * Jj + j) * Pp + hp * 8);
                float4 a = op[0], b4 = op[1];
                osum[bb][0] = a.x;  osum[bb][1] = a.y;  osum[bb][2] = a.z;  osum[bb][3] = a.w;
                osum[bb][4] = b4.x; osum[bb][5] = b4.y; osum[bb][6] = b4.z; osum[bb][7] = b4.w;
            }
        }

        float Sa[BT][8];
        #pragma unroll
        for (int bb = 0; bb < BT; ++bb)
            #pragma unroll
            for (int pp = 0; pp < 8; ++pp) Sa[bb][pp] = 0.f;

        load_slice(n0);
        store_slice(0);
        __syncthreads();

        for (int nn = 0; nn < BN; ++nn) {
            if (nn + 1 < BN) load_slice(n0 + nn + 1);  // prefetch next slice
            const int buf = nn & 1;

            // x rows (LDS broadcast, one b128 per batch): 8 halves = 4 half2
            half2v x01[BT], x23[BT], x45[BT], x67[BT];
            #pragma unroll
            for (int bb = 0; bb < BT; ++bb) {
                uint4 xr = xw[(size_t)bb * BN + nn];
                x01[bb] = bch2(xr.x); x23[bb] = bch2(xr.y);
                x45[bb] = bch2(xr.z); x67[bb] = bch2(xr.w);
            }

            // u_hat via fdot2 (f16 inputs, fp32 accumulate)
            float uh[BT][8];
            #pragma unroll
            for (int pp = 0; pp < 8; ++pp) {
                uint4 wv = wbuf[buf][pp * 64 + ((lane + pp) & 63)];
                half2v w01 = bch2(wv.x), w23 = bch2(wv.y);
                half2v w45 = bch2(wv.z), w67 = bch2(wv.w);
                #pragma unroll
                for (int bb = 0; bb < BT; ++bb) {
                    float acc = fdot2(w01, x01[bb], 0.f);
                    acc = fdot2(w23, x23[bb], acc);
                    acc = fdot2(w45, x45[bb], acc);
                    acc = fdot2(w67, x67[bb], acc);
                    uh[bb][pp] = acc;
                }
            }

            if (pass == 0) {   // wave-uniform branch
                #pragma unroll
                for (int bb = 0; bb < BT; ++bb)
                    #pragma unroll
                    for (int pp = 0; pp < 8; ++pp) Sa[bb][pp] += uh[bb][pp];
            } else {
                #pragma unroll
                for (int bb = 0; bb < BT; ++bb) {
                    float lg = 0.f;
                    #pragma unroll
                    for (int pp = 0; pp < 8; ++pp)
                        lg = fmaf(osum[bb][pp], uh[bb][pp], lg);
                    lg += __shfl_xor(lg, 1, 64);   // merge p-halves
                    float e = __expf(lg);
                    float se = e;
                    #pragma unroll
                    for (int mk = 2; mk <= 32; mk <<= 1)
                        se += __shfl_xor(se, mk, 64);
                    float c = e * __builtin_amdgcn_rcpf(se);
                    #pragma unroll
                    for (int pp = 0; pp < 8; ++pp)
                        Sa[bb][pp] = fmaf(c, uh[bb][pp], Sa[bb][pp]);
                }
            }

            if (nn + 1 < BN) {
                store_slice((nn + 1) & 1);
                __syncthreads();
            }
        }

        // ---- flush block-partial S into part nc (plain coalesced stores) ----
        #pragma unroll
        for (int bb = 0; bb < BT; ++bb) {
            const size_t off =
                ((size_t)(b0 + wave * BT + bb) * Jj + j) * Pp + hp * 8;
            float4* dst = reinterpret_cast<float4*>(Sp + (size_t)nc * SZ + off);
            dst[0] = make_float4(Sa[bb][0], Sa[bb][1], Sa[bb][2], Sa[bb][3]);
            dst[1] = make_float4(Sa[bb][4], Sa[bb][5], Sa[bb][6], Sa[bb][7]);
        }

        gbar(&bar[2 * pass], tid);    // all partials device-visible

        // ---- distributed reduce + squash: block owns 32 float4 of S ----
        {
            const float scale = (pass == 0) ? (1.f / (float)Jj) : 1.f;
            float4* scratch = reinterpret_cast<float4*>(wbuf);  // free now
            const int eL = tid >> 4;       // 0..31 local element
            const int sg = tid & 15;       // 16 part-groups
            const int e0 = blockIdx.x * 32;
            const float4* spf = reinterpret_cast<const float4*>(Sp);
            float4 a = make_float4(0.f, 0.f, 0.f, 0.f);
            #pragma unroll
            for (int s = 0; s < 4; ++s) {
                float4 v = spf[(size_t)(sg + 16 * s) * (SZ / 4) + e0 + eL];
                a.x += v.x; a.y += v.y; a.z += v.z; a.w += v.w;
            }
            scratch[eL * 16 + sg] = a;
            __syncthreads();
            if (tid < 32) {
                float4 v = make_float4(0.f, 0.f, 0.f, 0.f);
                #pragma unroll
                for (int k = 0; k < 16; ++k) {
                    float4 w = scratch[tid * 16 + k];
                    v.x += w.x; v.y += w.y; v.z += w.z; v.w += w.w;
                }
                v.x *= scale; v.y *= scale; v.z *= scale; v.w *= scale;
                float s2 = v.x * v.x + v.y * v.y + v.z * v.z + v.w * v.w;
                s2 += __shfl_xor(s2, 1, 64);  // (b,j) row = 4 consecutive tid
                s2 += __shfl_xor(s2, 2, 64);
                const float g = s2 / ((1.f + s2) * sqrtf(s2 + 1e-7f));
                float4 o = make_float4(g * v.x, g * v.y, g * v.z, g * v.w);
                const int E = e0 + tid;
                if (pass == 0) {
                    reinterpret_cast<float4*>(OS)[E] = o;
                } else if (pass == 1) {
                    float4 p = reinterpret_cast<float4*>(OS)[E];
                    p.x += o.x; p.y += o.y; p.z += o.z; p.w += o.w;
                    reinterpret_cast<float4*>(OS)[E] = p;
                } else {
                    reinterpret_cast<float4*>(out)[E] = o;
                }
            }
        }

        if (pass < 2) gbar(&bar[2 * pass + 1], tid);  // OS visible; wbuf free
    }
}

// ---------------- fallback path (small ws): R9 sequence ----------------
template<int LOGITS>
__global__ __launch_bounds__(512, 4)
void route_k(const float* __restrict__ x, const float* __restrict__ W,
             const float* __restrict__ OS, float* __restrict__ S)
{
    __shared__ uint4 wbuf[2][512];
    __shared__ uint4 xs[BB * BN];

    const int tid  = threadIdx.x;
    const int wave = tid >> 6;
    const int lane = tid & 63;
    const int id  = blockIdx.x;
    const int xcd = id & 7;
    const int bc  = (id >> 3) & 7;
    const int nch = id >> 6;
    const int nc  = xcd + 8 * nch;
    const int b0  = bc * BB;
    const int n0  = nc * BN;
    const int j   = lane >> 1;
    const int hp  = lane & 1;

    {
        const int b = tid >> 5, n = tid & 31;
        const float4* src = reinterpret_cast<const float4*>(
            x + ((size_t)(b0 + b) * Nn + n0 + n) * Dd);
        float4 a = src[0], c4 = src[1];
        uint4 o;
        o.x = pkh2(a.x, a.y);  o.y = pkh2(a.z, a.w);
        o.z = pkh2(c4.x, c4.y); o.w = pkh2(c4.z, c4.w);
        xs[b * BN + n] = o;
    }

    const float4* Wg = reinterpret_cast<const float4*>(W);
    const int sj = tid >> 4, sp = tid & 15;
    const int sl = sj * 2 + (sp >> 3), spp = sp & 7;
    const int wslot = spp * 64 + ((sl + spp) & 63);
    float4 sta, stb;
    auto load_slice = [&](int n) {
        const size_t base = (size_t)n * 32 + sp * 2 + (size_t)sj * ((size_t)Nn * 32);
        sta = Wg[base]; stb = Wg[base + 1];
    };
    auto store_slice = [&](int buf) {
        uint4 o;
        o.x = pkh2(sta.x, sta.y);  o.y = pkh2(sta.z, sta.w);
        o.z = pkh2(stb.x, stb.y);  o.w = pkh2(stb.z, stb.w);
        wbuf[buf][wslot] = o;
    };

    float osum[BT][8];
    if (LOGITS) {
        #pragma unroll
        for (int bb = 0; bb < BT; ++bb) {
            const float4* op = reinterpret_cast<const float4*>(
                OS + ((size_t)(b0 + wave * BT + bb) * Jj + j) * Pp + hp * 8);
            float4 a = op[0], b4 = op[1];
            osum[bb][0] = a.x;  osum[bb][1] = a.y;  osum[bb][2] = a.z;  osum[bb][3] = a.w;
            osum[bb][4] = b4.x; osum[bb][5] = b4.y; osum[bb][6] = b4.z; osum[bb][7] = b4.w;
        }
    }
    float Sa[BT][8];
    #pragma unroll
    for (int bb = 0; bb < BT; ++bb)
        #pragma unroll
        for (int pp = 0; pp < 8; ++pp) Sa[bb][pp] = 0.f;

    load_slice(n0); store_slice(0); __syncthreads();
    const uint4* xw = xs + (size_t)(wave * BT) * BN;

    for (int nn = 0; nn < BN; ++nn) {
        if (nn + 1 < BN) load_slice(n0 + nn + 1);
        const int buf = nn & 1;
        half2v x01[BT], x23[BT], x45[BT], x67[BT];
        #pragma unroll
        for (int bb = 0; bb < BT; ++bb) {
            uint4 xr = xw[(size_t)bb * BN + nn];
            x01[bb] = bch2(xr.x); x23[bb] = bch2(xr.y);
            x45[bb] = bch2(xr.z); x67[bb] = bch2(xr.w);
        }
        float uh[BT][8];
        #pragma unroll
        for (int pp = 0; pp < 8; ++pp) {
            uint4 wv = wbuf[buf][pp * 64 + ((lane + pp) & 63)];
            half2v w01 = bch2(wv.x), w23 = bch2(wv.y);
            half2v w45 = bch2(wv.z), w67 = bch2(wv.w);
            #pragma unroll
            for (int bb = 0; bb < BT; ++bb) {
                float acc = fdot2(w01, x01[bb], 0.f);
                acc = fdot2(w23, x23[bb], acc);
                acc = fdot2(w45, x45[bb], acc);
                acc = fdot2(w67, x67[bb], acc);
                uh[bb][pp] = acc;
            }
        }
        if (!LOGITS) {
            #pragma unroll
            for (int bb = 0; bb < BT; ++bb)
                #pragma unroll
                for (int pp = 0; pp < 8; ++pp) Sa[bb][pp] += uh[bb][pp];
        } else {
            #pragma unroll
            for (int bb = 0; bb < BT; ++bb) {
                float lg = 0.f;
                #pragma unroll
                for (int pp = 0; pp < 8; ++pp)
                    lg = fmaf(osum[bb][pp], uh[bb][pp], lg);
                lg += __shfl_xor(lg, 1, 64);
                float e = __expf(lg);
                float se = e;
                #pragma unroll
                for (int mk = 2; mk <= 32; mk <<= 1)
                    se += __shfl_xor(se, mk, 64);
                float c = e * __builtin_amdgcn_rcpf(se);
                #pragma unroll
                for (int pp = 0; pp < 8; ++pp)
                    Sa[bb][pp] = fmaf(c, uh[bb][pp], Sa[bb][pp]);
            }
        }
        if (nn + 1 < BN) { store_slice((nn + 1) & 1); __syncthreads(); }
    }
    #pragma unroll
    for (int bb = 0; bb < BT; ++bb) {
        const size_t off = ((size_t)(b0 + wave * BT + bb) * Jj + j) * Pp + hp * 8;
        float* spd = S + off;
        #pragma unroll
        for (int pp = 0; pp < 8; ++pp) atomicAdd(spd + pp, Sa[bb][pp]);
    }
}

__global__ void reduce_squash_k(const float* __restrict__ Sp, float scale,
                                float* __restrict__ OS, float* __restrict__ out,
                                int mode)
{
    const int t = blockIdx.x * 64 + threadIdx.x;
    float4 a = reinterpret_cast<const float4*>(Sp)[t];
    a.x *= scale; a.y *= scale; a.z *= scale; a.w *= scale;
    float s2 = a.x * a.x + a.y * a.y + a.z * a.z + a.w * a.w;
    s2 += __shfl_xor(s2, 1, 64);
    s2 += __shfl_xor(s2, 2, 64);
    const float g = s2 / ((1.f + s2) * sqrtf(s2 + 1e-7f));
    float4 v = make_float4(g * a.x, g * a.y, g * a.z, g * a.w);
    if (mode == 0) {
        reinterpret_cast<float4*>(OS)[t] = v;
    } else if (mode == 1) {
        float4 o = reinterpret_cast<float4*>(OS)[t];
        o.x += v.x; o.y += v.y; o.z += v.z; o.w += v.w;
        reinterpret_cast<float4*>(OS)[t] = o;
    } else {
        reinterpret_cast<float4*>(out)[t] = v;
    }
}

extern "C" void kernel_launch(void* const* d_in, const int* in_sizes, int n_in,
                              void* d_out, int out_size, void* d_ws, size_t ws_size,
                              hipStream_t stream)
{
    const float* x = (const float*)d_in[0];   // [128, 2048, 8]
    const float* W = (const float*)d_in[1];   // [32, 2048, 16, 8]
    float* out = (float*)d_out;               // [128, 32, 16]

    const size_t need = (size_t)(NNC + 1) * SZ * sizeof(float) + 64;
    const bool part = ws_size >= need;        // ~17 MB

    if (part) {
        float* Sp = (float*)d_ws;                     // [64][65536] partials
        float* OS = Sp + (size_t)NNC * SZ;            // running output sum
        unsigned* bar = (unsigned*)(OS + SZ);         // 5 barrier counters

        hipMemsetAsync(bar, 0, 64, stream);           // ws re-poisoned each call
        fused_k<<<dim3(GRID), dim3(512), 0, stream>>>(x, W, Sp, OS, out, bar);
    } else {
        float* S  = (float*)d_ws;
        float* OS = S + SZ;
        const size_t Sbytes = (size_t)SZ * sizeof(float);
        dim3 rg(GRID), rb(512);
        dim3 sg(SZ / 4 / 64), sb(64);

        hipMemsetAsync(S, 0, Sbytes, stream);
        route_k<0><<<rg, rb, 0, stream>>>(x, W, nullptr, S);
        reduce_squash_k<<<sg, sb, 0, stream>>>(S, 1.f / Jj, OS, out, 0);

        hipMemsetAsync(S, 0, Sbytes, stream);
        route_k<1><<<rg, rb, 0, stream>>>(x, W, OS, S);
        reduce_squash_k<<<sg, sb, 0, stream>>>(S, 1.f, OS, out, 1);

        hipMemsetAsync(S, 0, Sbytes, stream);
        route_k<1><<<rg, rb, 0, stream>>>(x, W, OS, S);
        reduce_squash_k<<<sg, sb, 0, stream>>>(S, 1.f, OS, out, 2);
    }
}

// Round 11
// 228.689 us; speedup vs baseline: 6.0660x; 6.0660x over previous
//
#include <hip/hip_runtime.h>
#include <math.h>

// Problem constants (fixed by setup_inputs)
constexpr int Bb = 128;   // batch
constexpr int Nn = 2048;  // input capsules
constexpr int Dd = 8;     // input capsule dim
constexpr int Jj = 32;    // output capsules
constexpr int Pp = 16;    // output capsule dim

// Tiling R11: BT=4 halves the dominant DS term (W ds_read_b128 per batch).
// 512-thread blocks, 8 waves, BT=4 -> BB=32 batches/block, GRID=256 (1/CU).
// __launch_bounds__(512,2) gives the allocator a 256-VGPR budget: the R5/R6
// BT=4 spills were caused by forced-128 caps, not by BT=4 itself.
constexpr int BT = 4;
constexpr int WV = 8;
constexpr int BB = BT * WV;      // 32 batches per block
constexpr int BN = 32;           // n per block
constexpr int NBC = Bb / BB;     // 4
constexpr int NNC = Nn / BN;     // 64
constexpr int GRID = NBC * NNC;  // 256
constexpr int SZ = Bb * Jj * Pp; // 65536 floats

typedef _Float16 half2v __attribute__((ext_vector_type(2)));

#if __has_builtin(__builtin_amdgcn_fdot2)
__device__ inline float fdot2(half2v a, half2v b, float c) {
    return __builtin_amdgcn_fdot2(a, b, c, false);
}
#else
__device__ inline float fdot2(half2v a, half2v b, float c) {
    return (float)a.x * (float)b.x + (float)a.y * (float)b.y + c;
}
#endif

__device__ inline half2v bch2(unsigned u) { return __builtin_bit_cast(half2v, u); }
__device__ inline unsigned pkh2(float lo, float hi) {
    half2v h; h.x = (_Float16)lo; h.y = (_Float16)hi;   // v_cvt_f16_f32 (RTN)
    return __builtin_bit_cast(unsigned, h);
}

// Routing pass. R7/R9 body with BT=4. W staged per-n in LDS as fp16
// (8 KB/slice, double-buffered), x tile fp16, u_hat via v_dot2_f32_f16.
// Swizzled W layout: chunk (l = j*2+hp, pp) at slot pp*64 + ((l+pp)&63)
// (proven zero-conflict). XCD swizzle: the 4 bc-sharers of an n-chunk share
// blockIdx&7 (R4-verified L2 locality).
// Lessons: R5/R6 spills = forced VGPR caps (avoided here via (512,2));
// R8 cooperative launch unsupported; R10 manual grid barrier ~240us/barrier
// (cross-XCD coherence) -- 6-dispatch pipeline is the final architecture.
template<int LOGITS, int ATOMIC>
__global__ __launch_bounds__(512, 2)
void route_k(const float* __restrict__ x, const float* __restrict__ W,
             const float* __restrict__ OS, float* __restrict__ S)
{
    __shared__ uint4 wbuf[2][512];   // 2 x 8 KB fp16 W double buffer
    __shared__ uint4 xs[BB * BN];    // 16 KB fp16 x tile: [b][n] -> 8 halves

    const int tid  = threadIdx.x;
    const int wave = tid >> 6;
    const int lane = tid & 63;

    const int id  = blockIdx.x;
    const int xcd = id & 7;
    const int bc  = (id >> 3) & 3;         // 0..3
    const int nch = id >> 5;               // 0..7
    const int nc  = xcd + 8 * nch;         // 0..63
    const int b0  = bc * BB;
    const int n0  = nc * BN;
    const int j   = lane >> 1;
    const int hp  = lane & 1;              // p-half

    // ---- stage x tile as fp16: thread t -> rows (t>>5) and (t>>5)+16 ----
    {
        const int b = tid >> 5, n = tid & 31;
        #pragma unroll
        for (int r = 0; r < 2; ++r) {
            const float4* src = reinterpret_cast<const float4*>(
                x + ((size_t)(b0 + b + 16 * r) * Nn + n0 + n) * Dd);
            float4 a = src[0], c4 = src[1];
            uint4 o;
            o.x = pkh2(a.x, a.y);  o.y = pkh2(a.z, a.w);
            o.z = pkh2(c4.x, c4.y); o.w = pkh2(c4.z, c4.w);
            xs[(b + 16 * r) * BN + n] = o;
        }
    }

    // ---- W staging: thread t -> (j = t>>4, p = t&15); 2 float4 -> 1 uint4 ----
    const float4* Wg = reinterpret_cast<const float4*>(W);
    const int sj = tid >> 4;                    // j
    const int sp = tid & 15;                    // p
    const int sl = sj * 2 + (sp >> 3);          // l for this chunk
    const int spp = sp & 7;                     // pp
    const int wslot = spp * 64 + ((sl + spp) & 63);

    float4 sta, stb;
    auto load_slice = [&](int n) {
        const size_t base = (size_t)n * 32 + sp * 2 + (size_t)sj * ((size_t)Nn * 32);
        sta = Wg[base];
        stb = Wg[base + 1];
    };
    auto store_slice = [&](int buf) {
        uint4 o;
        o.x = pkh2(sta.x, sta.y);  o.y = pkh2(sta.z, sta.w);
        o.z = pkh2(stb.x, stb.y);  o.w = pkh2(stb.z, stb.w);
        wbuf[buf][wslot] = o;
    };

    // Output-sum fragment for logits
    float osum[BT][8];
    if (LOGITS) {
        #pragma unroll
        for (int bb = 0; bb < BT; ++bb) {
            const float4* op = reinterpret_cast<const float4*>(
                OS + ((size_t)(b0 + wave * BT + bb) * Jj + j) * Pp + hp * 8);
            float4 a = op[0], b4 = op[1];
            osum[bb][0] = a.x;  osum[bb][1] = a.y;  osum[bb][2] = a.z;  osum[bb][3] = a.w;
            osum[bb][4] = b4.x; osum[bb][5] = b4.y; osum[bb][6] = b4.z; osum[bb][7] = b4.w;
        }
    }

    float Sa[BT][8];
    #pragma unroll
    for (int bb = 0; bb < BT; ++bb)
        #pragma unroll
        for (int pp = 0; pp < 8; ++pp) Sa[bb][pp] = 0.f;

    load_slice(n0);
    store_slice(0);
    __syncthreads();

    const uint4* xw = xs + (size_t)(wave * BT) * BN;   // this wave's x rows

    for (int nn = 0; nn < BN; ++nn) {
        if (nn + 1 < BN) load_slice(n0 + nn + 1);  // prefetch next slice to regs
        const int buf = nn & 1;

        // x rows (LDS broadcast, one b128 per batch): 8 halves = 4 half2
        half2v x01[BT], x23[BT], x45[BT], x67[BT];
        #pragma unroll
        for (int bb = 0; bb < BT; ++bb) {
            uint4 xr = xw[(size_t)bb * BN + nn];
            x01[bb] = bch2(xr.x); x23[bb] = bch2(xr.y);
            x45[bb] = bch2(xr.z); x67[bb] = bch2(xr.w);
        }

        // u_hat via fdot2 (f16 inputs, fp32 accumulate); W read amortized 4x
        float uh[BT][8];
        #pragma unroll
        for (int pp = 0; pp < 8; ++pp) {
            uint4 wv = wbuf[buf][pp * 64 + ((lane + pp) & 63)];
            half2v w01 = bch2(wv.x), w23 = bch2(wv.y);
            half2v w45 = bch2(wv.z), w67 = bch2(wv.w);
            #pragma unroll
            for (int bb = 0; bb < BT; ++bb) {
                float acc = fdot2(w01, x01[bb], 0.f);
                acc = fdot2(w23, x23[bb], acc);
                acc = fdot2(w45, x45[bb], acc);
                acc = fdot2(w67, x67[bb], acc);
                uh[bb][pp] = acc;
            }
        }

        if (!LOGITS) {
            #pragma unroll
            for (int bb = 0; bb < BT; ++bb)
                #pragma unroll
                for (int pp = 0; pp < 8; ++pp) Sa[bb][pp] += uh[bb][pp];
        } else {
            #pragma unroll
            for (int bb = 0; bb < BT; ++bb) {
                float lg = 0.f;
                #pragma unroll
                for (int pp = 0; pp < 8; ++pp)
                    lg = fmaf(osum[bb][pp], uh[bb][pp], lg);
                lg += __shfl_xor(lg, 1, 64);   // merge p-halves: full 16-p dot
                // softmax over j (no max-subtract; |lg| small): butterfly
                float e = __expf(lg);
                float se = e;
                #pragma unroll
                for (int mk = 2; mk <= 32; mk <<= 1)
                    se += __shfl_xor(se, mk, 64);
                float c = e * __builtin_amdgcn_rcpf(se);
                #pragma unroll
                for (int pp = 0; pp < 8; ++pp)
                    Sa[bb][pp] = fmaf(c, uh[bb][pp], Sa[bb][pp]);
            }
        }

        if (nn + 1 < BN) {
            store_slice((nn + 1) & 1);
            __syncthreads();
        }
    }

    // ---- flush block-partial S ----
    #pragma unroll
    for (int bb = 0; bb < BT; ++bb) {
        const size_t off = ((size_t)(b0 + wave * BT + bb) * Jj + j) * Pp + hp * 8;
        if (ATOMIC) {
            float* spd = S + off;
            #pragma unroll
            for (int pp = 0; pp < 8; ++pp) atomicAdd(spd + pp, Sa[bb][pp]);
        } else {
            float4* dst = reinterpret_cast<float4*>(S + (size_t)nc * SZ + off);
            dst[0] = make_float4(Sa[bb][0], Sa[bb][1], Sa[bb][2], Sa[bb][3]);
            dst[1] = make_float4(Sa[bb][4], Sa[bb][5], Sa[bb][6], Sa[bb][7]);
        }
    }
}

// Reduce nparts partial S slices, then squash.
// mode 0: OS = v; 1: OS += v; 2: out = v.  256 blocks x 64 threads (R9).
__global__ void reduce_squash_k(const float* __restrict__ Sp, int nparts,
                                float scale, float* __restrict__ OS,
                                float* __restrict__ out, int mode)
{
    const int t = blockIdx.x * 64 + threadIdx.x;   // 0..16383
    const float4* sp = reinterpret_cast<const float4*>(Sp);
    float4 a = make_float4(0.f, 0.f, 0.f, 0.f);
    #pragma unroll 8
    for (int s = 0; s < nparts; ++s) {
        float4 v = sp[(size_t)s * (SZ / 4) + t];
        a.x += v.x; a.y += v.y; a.z += v.z; a.w += v.w;
    }
    a.x *= scale; a.y *= scale; a.z *= scale; a.w *= scale;
    float s2 = a.x * a.x + a.y * a.y + a.z * a.z + a.w * a.w;
    s2 += __shfl_xor(s2, 1, 64);   // 16 p = 4 consecutive threads
    s2 += __shfl_xor(s2, 2, 64);
    const float g = s2 / ((1.f + s2) * sqrtf(s2 + 1e-7f));
    float4 v = make_float4(g * a.x, g * a.y, g * a.z, g * a.w);
    if (mode == 0) {
        reinterpret_cast<float4*>(OS)[t] = v;
    } else if (mode == 1) {
        float4 o = reinterpret_cast<float4*>(OS)[t];
        o.x += v.x; o.y += v.y; o.z += v.z; o.w += v.w;
        reinterpret_cast<float4*>(OS)[t] = o;
    } else {
        reinterpret_cast<float4*>(out)[t] = v;
    }
}

extern "C" void kernel_launch(void* const* d_in, const int* in_sizes, int n_in,
                              void* d_out, int out_size, void* d_ws, size_t ws_size,
                              hipStream_t stream)
{
    const float* x = (const float*)d_in[0];   // [128, 2048, 8]
    const float* W = (const float*)d_in[1];   // [32, 2048, 16, 8]
    float* out = (float*)d_out;               // [128, 32, 16]

    const bool part = ws_size >= (size_t)(NNC + 1) * SZ * sizeof(float); // 16.9 MB
    dim3 rg(GRID), rb(512);
    dim3 sg(SZ / 4 / 64), sb(64);             // 256 blocks x 64 threads

    if (part) {
        float* Sp = (float*)d_ws;                 // [64][65536] partials
        float* OS = Sp + (size_t)NNC * SZ;        // running output sum

        route_k<0, 0><<<rg, rb, 0, stream>>>(x, W, nullptr, Sp);
        reduce_squash_k<<<sg, sb, 0, stream>>>(Sp, NNC, 1.f / Jj, OS, out, 0);

        route_k<1, 0><<<rg, rb, 0, stream>>>(x, W, OS, Sp);
        reduce_squash_k<<<sg, sb, 0, stream>>>(Sp, NNC, 1.f, OS, out, 1);

        route_k<1, 0><<<rg, rb, 0, stream>>>(x, W, OS, Sp);
        reduce_squash_k<<<sg, sb, 0, stream>>>(Sp, NNC, 1.f, OS, out, 2);
    } else {
        float* S  = (float*)d_ws;
        float* OS = S + SZ;
        const size_t Sbytes = (size_t)SZ * sizeof(float);

        hipMemsetAsync(S, 0, Sbytes, stream);
        route_k<0, 1><<<rg, rb, 0, stream>>>(x, W, nullptr, S);
        reduce_squash_k<<<sg, sb, 0, stream>>>(S, 1, 1.f / Jj, OS, out, 0);

        hipMemsetAsync(S, 0, Sbytes, stream);
        route_k<1, 1><<<rg, rb, 0, stream>>>(x, W, OS, S);
        reduce_squash_k<<<sg, sb, 0, stream>>>(S, 1, 1.f, OS, out, 1);

        hipMemsetAsync(S, 0, Sbytes, stream);
        route_k<1, 1><<<rg, rb, 0, stream>>>(x, W, OS, S);
        reduce_squash_k<<<sg, sb, 0, stream>>>(S, 1, 1.f, OS, out, 2);
    }
}